// Round 17
// baseline (101.668 us; speedup 1.0000x reference)
//
#include <hip/hip_runtime.h>
#include <hip/hip_bf16.h>

// MultiEdgeTypePredictor — R14: proj v4 (double-buffered chunk pipeline +
// direct P stores) and edge with hoisted B2 fragments.
//
//   Psrc = h_src @ W1[:256,:] ; Pdst = h_dst @ W1[256:,:] + b1   (bf16, d_ws)
//   x[e] = relu(Psrc[s[e]] + Pdst[d[e]]) * sc + sh ; GEMM2 ; GEMM3
//
//   proj v4: K=256 in 2 chunks of 128; LDS double-buffer (2x17.4KB); per
//   phase: LOAD(c+1)->regs, PIN, MFMA(c), [direct P store at tile end],
//   ds_write(c+1), bar. Fully unrolled (static reg indexing). P written
//   straight from acc regs (no LDS epilogue, no extra barriers).
//   edge: B2 frags (block-invariant) loaded into regs at kernel entry so
//   their L2 latency hides under index-load + gather.

typedef __attribute__((ext_vector_type(8))) short bf16x8;
typedef __attribute__((ext_vector_type(4))) float f32x4;
typedef __attribute__((ext_vector_type(8))) unsigned short u16x8;

constexpr int HID   = 128;
constexpr int ETILE = 64;
constexpr int AS    = 72;    // fallback chunk stride (bf16 elems)
constexpr int XS    = 136;   // edge x-tile row stride (bf16 elems, 272B)
constexpr int CS    = 136;   // proj chunk row stride (128 cols + 8 pad)

__device__ inline ushort f2bf(float f) {
    union { __hip_bfloat16 h; ushort u; } cv;
    cv.h = __float2bfloat16(f);   // RNE
    return cv.u;
}
__device__ inline float bf2f(ushort u) {
    return __uint_as_float(((unsigned int)u) << 16);
}

// ---------------- prep: pack weights + fold BN/emb ----------------
__global__ __launch_bounds__(256)
void prep_kernel(const float* __restrict__ W1, const float* __restrict__ W2,
                 const float* __restrict__ bn_gamma, const float* __restrict__ bn_beta,
                 const float* __restrict__ bn_mean, const float* __restrict__ bn_var,
                 const float* __restrict__ emb, const int* __restrict__ etype,
                 ushort* __restrict__ B1p, ushort* __restrict__ B2p,
                 float* __restrict__ sc, float* __restrict__ sh)
{
    int i = blockIdx.x * blockDim.x + threadIdx.x;
    if (i < 65536) {
        // B1 frag: i = ((ks*8 + ct)*64 + lane)*8 + j ; k = ks*32+(lane>>4)*8+j ; c = ct*16+(lane&15)
        int j = i & 7, lane = (i >> 3) & 63, ct = (i >> 9) & 7, ks = i >> 12;
        int k = ks * 32 + (lane >> 4) * 8 + j;
        int c = ct * 16 + (lane & 15);
        B1p[i] = f2bf(W1[k * HID + c]);
    } else if (i < 65536 + 8192) {
        int p = i - 65536;
        int j = p & 7, lane = (p >> 3) & 63, ct = (p >> 9) & 3, ks = p >> 11;
        int k = ks * 32 + (lane >> 4) * 8 + j;
        int c = ct * 16 + (lane & 15);
        B2p[p] = f2bf(W2[k * 64 + c]);
    } else if (i < 65536 + 8192 + HID) {
        int c = i - 65536 - 8192;
        float s = bn_gamma[c] * rsqrtf(bn_var[c] + 1e-5f);
        sc[c] = s;
        sh[c] = bn_beta[c] - bn_mean[c] * s + emb[etype[0] * HID + c];
    }
}

// ---------------- proj v4: P = h @ W1_half (+b1 on dst half) ----------------
// grid = nblk blocks; block b does tiles {b, b+nblk, b+2*nblk} per half.
__global__ __launch_bounds__(256)
void proj_kernel(const float* __restrict__ h_src, const float* __restrict__ h_dst,
                 const ushort* __restrict__ B1p, const float* __restrict__ b1,
                 ushort* __restrict__ Psrc, ushort* __restrict__ Pdst,
                 int n_nodes, int ntiles, int nblk)
{
    __shared__ ushort sA[2][ETILE * CS];   // 2 x 17408 B chunk buffers

    const int t    = threadIdx.x;
    const int lane = t & 63;
    const int w    = t >> 6;
    const int lr   = lane & 15;
    const int lq   = lane >> 4;

    float4 rg[8];                          // stage regs: 64 rows x 128 cols / 256 thr

    // chunk c (0..5): tile idx = blockIdx.x + (c>>1)*nblk, col half = (c&1)
#define LOADP(c) do {                                                          \
        const int tile_ = blockIdx.x + ((c) >> 1) * nblk;                      \
        const int nb_   = tile_ * 64;                                          \
        _Pragma("unroll")                                                      \
        for (int i = 0; i < 8; ++i) {                                          \
            int f = t + i * 256;                                               \
            int e = f >> 5, q = f & 31;                                        \
            int row = nb_ + e;                                                 \
            if (row >= n_nodes) row = n_nodes - 1;                             \
            rg[i] = *reinterpret_cast<const float4*>(                          \
                hp + (size_t)row * 256 + ((c) & 1) * 128 + q * 4);             \
        } } while (0)

#define STOREP(B) do {                                                         \
        _Pragma("unroll")                                                      \
        for (int i = 0; i < 8; ++i) {                                          \
            int f = t + i * 256;                                               \
            int e = f >> 5, q = f & 31;                                        \
            ushort4 bv;                                                        \
            bv.x = f2bf(rg[i].x); bv.y = f2bf(rg[i].y);                        \
            bv.z = f2bf(rg[i].z); bv.w = f2bf(rg[i].w);                        \
            *reinterpret_cast<ushort4*>(&sA[B][e * CS + q * 4]) = bv;          \
        } } while (0)

    // MFMA chunk: 4 ksteps x 4 row-tiles x 2 col-tiles; B from regs (static idx)
#define PCOMP(B, kc) do {                                                      \
        _Pragma("unroll")                                                      \
        for (int ks = 0; ks < 4; ++ks)                                         \
        _Pragma("unroll")                                                      \
        for (int rt = 0; rt < 4; ++rt) {                                       \
            bf16x8 af = *reinterpret_cast<const bf16x8*>(                      \
                &sA[B][(rt * 16 + lr) * CS + ks * 32 + lq * 8]);               \
            acc[rt][0] = __builtin_amdgcn_mfma_f32_16x16x32_bf16(af, bfr[(kc) * 4 + ks][0], acc[rt][0], 0, 0, 0); \
            acc[rt][1] = __builtin_amdgcn_mfma_f32_16x16x32_bf16(af, bfr[(kc) * 4 + ks][1], acc[rt][1], 0, 0, 0); \
        } } while (0)

#define PSTORE(c) do {                                                         \
        const int tile_ = blockIdx.x + ((c) >> 1) * nblk;                      \
        const int nb_   = tile_ * 64;                                          \
        _Pragma("unroll")                                                      \
        for (int ctl = 0; ctl < 2; ++ctl)                                      \
        _Pragma("unroll")                                                      \
        for (int rt = 0; rt < 4; ++rt)                                         \
        _Pragma("unroll")                                                      \
        for (int r = 0; r < 4; ++r) {                                          \
            int row = nb_ + rt * 16 + lq * 4 + r;                              \
            if (row < n_nodes)                                                 \
                Pp[(size_t)row * 128 + (2 * w + ctl) * 16 + lr] =              \
                    f2bf(acc[rt][ctl][r] + b1v[ctl]);                          \
        } } while (0)

#define ZACC() do {                                                            \
        _Pragma("unroll")                                                      \
        for (int rt = 0; rt < 4; ++rt) {                                       \
            acc[rt][0] = (f32x4)0.0f; acc[rt][1] = (f32x4)0.0f;                \
        } } while (0)

#define PIN() __builtin_amdgcn_sched_barrier(0)

#pragma unroll 1
    for (int half = 0; half < 2; ++half) {
        const float* hp = half ? h_dst : h_src;
        ushort* Pp      = half ? Pdst : Psrc;

        // hoisted B fragments for this half: 8 ksteps x 2 col-tiles
        bf16x8 bfr[8][2];
#pragma unroll
        for (int ks = 0; ks < 8; ++ks)
#pragma unroll
            for (int ctl = 0; ctl < 2; ++ctl)
                bfr[ks][ctl] = *reinterpret_cast<const bf16x8*>(
                    B1p + (size_t)(((half * 8 + ks) * 8 + 2 * w + ctl) * 64 + lane) * 8);

        float b1v[2] = {0.0f, 0.0f};
        if (half) {
            b1v[0] = b1[(2 * w) * 16 + lr];
            b1v[1] = b1[(2 * w + 1) * 16 + lr];
        }

        f32x4 acc[4][2];

        __syncthreads();               // prev half's sA readers done
        LOADP(0); STOREP(0);
        __syncthreads();

        // c=0
        LOADP(1);  PIN();  ZACC();  PCOMP(0, 0);                 STOREP(1);  __syncthreads();
        // c=1 (tile 0 done)
        LOADP(2);  PIN();           PCOMP(1, 1);  PSTORE(1);     STOREP(0);  __syncthreads();
        // c=2
        LOADP(3);  PIN();  ZACC();  PCOMP(0, 0);                 STOREP(1);  __syncthreads();
        // c=3 (tile 1 done)
        LOADP(4);  PIN();           PCOMP(1, 1);  PSTORE(3);     STOREP(0);  __syncthreads();
        // c=4
        LOADP(5);  PIN();  ZACC();  PCOMP(0, 0);                 STOREP(1);  __syncthreads();
        // c=5 (tile 2 done)
                                    PCOMP(1, 1);  PSTORE(5);
    }

#undef LOADP
#undef STOREP
#undef PCOMP
#undef PSTORE
#undef ZACC
#undef PIN
}

// ---------------- edge: hoisted B2 + coalesced gather + GEMM2/3 ----------------
__global__ __launch_bounds__(256)
void edge_kernel(const ushort* __restrict__ Psrc, const ushort* __restrict__ Pdst,
                 const int* __restrict__ src_nodes, const int* __restrict__ dst_nodes,
                 const float* __restrict__ sc, const float* __restrict__ sh,
                 const float* __restrict__ b2, const float* __restrict__ W3,
                 const float* __restrict__ b3, const ushort* __restrict__ B2p,
                 float* __restrict__ out, int n_edges)
{
    __shared__ ushort sX[ETILE * XS];
    __shared__ int s_s[ETILE], s_d[ETILE];

    const int t     = threadIdx.x;
    const int lane  = t & 63;
    const int w     = t >> 6;
    const int lr    = lane & 15;
    const int lq    = lane >> 4;
    const int ebase = blockIdx.x * ETILE;

    // hoist B2 fragments (block-invariant): in flight during index load + gather
    bf16x8 b2r[4][4];   // [ks][ct]
#pragma unroll
    for (int ks = 0; ks < 4; ++ks)
#pragma unroll
        for (int ct = 0; ct < 4; ++ct)
            b2r[ks][ct] = *reinterpret_cast<const bf16x8*>(
                B2p + (size_t)((ks * 4 + ct) * 64 + lane) * 8);

    if (t < ETILE) {
        int e = ebase + t;
        s_s[t] = src_nodes[e < n_edges ? e : (n_edges - 1)];
    } else if (t < 2 * ETILE) {
        int e = ebase + t - ETILE;
        s_d[t - ETILE] = dst_nodes[e < n_edges ? e : (n_edges - 1)];
    }
    __syncthreads();

    // gather: 16 lanes per P row (256B contiguous segments)
    const int eg = w * 16 + lq;
    const int ch = lr;
    u16x8 gs[4], gd[4];
#pragma unroll
    for (int j = 0; j < 4; ++j)
        gs[j] = *reinterpret_cast<const u16x8*>(
            Psrc + (size_t)s_s[eg + j * 4] * 128 + ch * 8);
#pragma unroll
    for (int j = 0; j < 4; ++j)
        gd[j] = *reinterpret_cast<const u16x8*>(
            Pdst + (size_t)s_d[eg + j * 4] * 128 + ch * 8);
    asm volatile("" :: "v"(gs[0]), "v"(gs[1]), "v"(gs[2]), "v"(gs[3]),
                       "v"(gd[0]), "v"(gd[1]), "v"(gd[2]), "v"(gd[3]));

    // decode: relu(a+b) * sc + sh -> x (bf16) in LDS
    const int c0 = ch * 8;
    float4 sca = *reinterpret_cast<const float4*>(sc + c0);
    float4 scb = *reinterpret_cast<const float4*>(sc + c0 + 4);
    float4 sha = *reinterpret_cast<const float4*>(sh + c0);
    float4 shb = *reinterpret_cast<const float4*>(sh + c0 + 4);
    float ss[8] = {sca.x, sca.y, sca.z, sca.w, scb.x, scb.y, scb.z, scb.w};
    float zz[8] = {sha.x, sha.y, sha.z, sha.w, shb.x, shb.y, shb.z, shb.w};
#pragma unroll
    for (int j = 0; j < 4; ++j) {
        u16x8 xo;
#pragma unroll
        for (int i = 0; i < 8; ++i) {
            float v = bf2f((ushort)gs[j][i]) + bf2f((ushort)gd[j][i]);
            v = fmaxf(v, 0.0f);
            xo[i] = f2bf(fmaf(v, ss[i], zz[i]));
        }
        *reinterpret_cast<u16x8*>(&sX[(eg + j * 4) * XS + c0]) = xo;
    }
    __syncthreads();

    // -------- GEMM2 (B from regs) --------
    f32x4 acc2[4];
#pragma unroll
    for (int ct = 0; ct < 4; ++ct) acc2[ct] = (f32x4)0.0f;

#pragma unroll
    for (int ks = 0; ks < 4; ++ks) {
        bf16x8 af = *reinterpret_cast<const bf16x8*>(
            &sX[(w * 16 + lr) * XS + ks * 32 + lq * 8]);
#pragma unroll
        for (int ct = 0; ct < 4; ++ct)
            acc2[ct] = __builtin_amdgcn_mfma_f32_16x16x32_bf16(af, b2r[ks][ct], acc2[ct], 0, 0, 0);
    }

    // -------- GEMM3 --------
    float w3v[4], b2v[4];
#pragma unroll
    for (int ct = 0; ct < 4; ++ct) {
        int c = ct * 16 + lr;
        w3v[ct] = W3[c];
        b2v[ct] = b2[c];
    }
#pragma unroll
    for (int r = 0; r < 4; ++r) {
        float sum = 0.0f;
#pragma unroll
        for (int ct = 0; ct < 4; ++ct)
            sum += fmaxf(acc2[ct][r] + b2v[ct], 0.0f) * w3v[ct];
        sum += __shfl_xor(sum, 1);
        sum += __shfl_xor(sum, 2);
        sum += __shfl_xor(sum, 4);
        sum += __shfl_xor(sum, 8);
        int eo = ebase + w * 16 + lq * 4 + r;
        if (lr == 0 && eo < n_edges) out[eo] = sum + b3[0];
    }
}

// ================= fallback: R10 champion fused path (97.7us) =================
__global__ __launch_bounds__(256, 3)
void edge_mlp_mfma(const float* __restrict__ h_src, const float* __restrict__ h_dst,
                   const int* __restrict__ src_nodes, const int* __restrict__ dst_nodes,
                   const ushort* __restrict__ B1p, const ushort* __restrict__ B2p,
                   const float* __restrict__ b1, const float* __restrict__ sc,
                   const float* __restrict__ sh, const float* __restrict__ b2,
                   const float* __restrict__ W3, const float* __restrict__ b3,
                   float* __restrict__ out, int n_edges)
{
    __shared__ ushort sA[2][ETILE * AS];
    __shared__ int s_src[ETILE], s_dst[ETILE];

    const int t    = threadIdx.x;
    const int lane = t & 63;
    const int w    = t >> 6;
    const int lr   = lane & 15;
    const int lq   = lane >> 4;
    const int ebase = blockIdx.x * ETILE;

    if (t < ETILE) {
        int e = ebase + t;
        s_src[t] = src_nodes[e < n_edges ? e : 0];
    } else if (t < 2 * ETILE) {
        int e = ebase + t - ETILE;
        s_dst[t - ETILE] = dst_nodes[e < n_edges ? e : 0];
    }

    f32x4 acc[4][2];
#pragma unroll
    for (int rt = 0; rt < 4; ++rt)
#pragma unroll
        for (int c = 0; c < 2; ++c) acc[rt][c] = (f32x4)0.0f;

    float4 rA[4], rB[4];
    bf16x8 Bf0[4], Bf1[4];

#define PHASE_BAR() do {                                                       \
        asm volatile("s_waitcnt lgkmcnt(0)" ::: "memory");                     \
        __builtin_amdgcn_s_barrier();                                          \
    } while (0)
#define PIN() __builtin_amdgcn_sched_barrier(0)

#define LOADC(kc, R) do {                                                      \
        const float* hp = ((kc) < 4) ? h_src : h_dst;                          \
        const int* sidx = ((kc) < 4) ? s_src : s_dst;                          \
        const int koff = ((kc) & 3) * 64;                                      \
        _Pragma("unroll")                                                      \
        for (int i = 0; i < 4; ++i) {                                          \
            int f = t + i * 256; int e = f >> 4; int q = f & 15;               \
            R[i] = *reinterpret_cast<const float4*>(                           \
                hp + (size_t)sidx[e] * 256 + koff + q * 4);                    \
        } } while (0)

#define BLOAD(kc, BR) do {                                                     \
        _Pragma("unroll")                                                      \
        for (int s = 0; s < 2; ++s)                                            \
        _Pragma("unroll")                                                      \
        for (int c = 0; c < 2; ++c)                                            \
            BR[s * 2 + c] = *reinterpret_cast<const bf16x8*>(                  \
                B1p + (size_t)((((kc) * 2 + s) * 8 + 2 * w + c) * 64 + lane) * 8); \
        } while (0)

#define STOREC(B, R) do {                                                      \
        _Pragma("unroll")                                                      \
        for (int i = 0; i < 4; ++i) {                                          \
            int f = t + i * 256; int e = f >> 4; int q = f & 15;               \
            ushort4 bv;                                                        \
            bv.x = f2bf(R[i].x); bv.y = f2bf(R[i].y);                          \
            bv.z = f2bf(R[i].z); bv.w = f2bf(R[i].w);                          \
            *reinterpret_cast<ushort4*>(&sA[B][e * AS + q * 4]) = bv;          \
        } } while (0)

#define COMPF(B, BR) do {                                                      \
        _Pragma("unroll")                                                      \
        for (int ks = 0; ks < 2; ++ks) {                                       \
            _Pragma("unroll")                                                  \
            for (int rt = 0; rt < 4; ++rt) {                                   \
                bf16x8 af = *reinterpret_cast<const bf16x8*>(                  \
                    &sA[B][(rt * 16 + lr) * AS + ks * 32 + lq * 8]);           \
                acc[rt][0] = __builtin_amdgcn_mfma_f32_16x16x32_bf16(af, BR[ks * 2 + 0], acc[rt][0], 0, 0, 0); \
                acc[rt][1] = __builtin_amdgcn_mfma_f32_16x16x32_bf16(af, BR[ks * 2 + 1], acc[rt][1], 0, 0, 0); \
            } } } while (0)

    __syncthreads();

    LOADC(0, rA);
    BLOAD(0, Bf0);
    STOREC(0, rA);
    LOADC(1, rB);
    BLOAD(1, Bf1);
    PHASE_BAR();

    LOADC(2, rA);  PIN();  COMPF(0, Bf0);  BLOAD(2, Bf0);  STOREC(1, rB);  PHASE_BAR();
    LOADC(3, rB);  PIN();  COMPF(1, Bf1);  BLOAD(3, Bf1);  STOREC(0, rA);  PHASE_BAR();
    LOADC(4, rA);  PIN();  COMPF(0, Bf0);  BLOAD(4, Bf0);  STOREC(1, rB);  PHASE_BAR();
    LOADC(5, rB);  PIN();  COMPF(1, Bf1);  BLOAD(5, Bf1);  STOREC(0, rA);  PHASE_BAR();
    LOADC(6, rA);  PIN();  COMPF(0, Bf0);  BLOAD(6, Bf0);  STOREC(1, rB);  PHASE_BAR();
    LOADC(7, rB);  PIN();  COMPF(1, Bf1);  BLOAD(7, Bf1);  STOREC(0, rA);  PHASE_BAR();
                           COMPF(0, Bf0);                  STOREC(1, rB);  PHASE_BAR();
                           COMPF(1, Bf1);

#undef LOADC
#undef BLOAD
#undef STOREC
#undef COMPF
#undef PIN
#undef PHASE_BAR

    __syncthreads();
    ushort* sX = &sA[0][0];
#pragma unroll
    for (int ctl = 0; ctl < 2; ++ctl) {
        int c = (2 * w + ctl) * 16 + lr;
        float bb = b1[c], s = sc[c], z = sh[c];
#pragma unroll
        for (int rt = 0; rt < 4; ++rt)
#pragma unroll
            for (int r = 0; r < 4; ++r) {
                float x = fmaxf(acc[rt][ctl][r] + bb, 0.0f);
                sX[(rt * 16 + lq * 4 + r) * XS + c] = f2bf(fmaf(x, s, z));
            }
    }
    __syncthreads();

    f32x4 acc2[4];
#pragma unroll
    for (int ct = 0; ct < 4; ++ct) acc2[ct] = (f32x4)0.0f;

#pragma unroll
    for (int ks = 0; ks < 4; ++ks) {
        bf16x8 af = *reinterpret_cast<const bf16x8*>(
            &sX[(w * 16 + lr) * XS + ks * 32 + lq * 8]);
#pragma unroll
        for (int ct = 0; ct < 4; ++ct) {
            bf16x8 bf = *reinterpret_cast<const bf16x8*>(
                B2p + (size_t)((ks * 4 + ct) * 64 + lane) * 8);
            acc2[ct] = __builtin_amdgcn_mfma_f32_16x16x32_bf16(af, bf, acc2[ct], 0, 0, 0);
        }
    }

    float w3v[4], b2v[4];
#pragma unroll
    for (int ct = 0; ct < 4; ++ct) {
        int c = ct * 16 + lr;
        w3v[ct] = W3[c];
        b2v[ct] = b2[c];
    }
#pragma unroll
    for (int r = 0; r < 4; ++r) {
        float sum = 0.0f;
#pragma unroll
        for (int ct = 0; ct < 4; ++ct)
            sum += fmaxf(acc2[ct][r] + b2v[ct], 0.0f) * w3v[ct];
        sum += __shfl_xor(sum, 1);
        sum += __shfl_xor(sum, 2);
        sum += __shfl_xor(sum, 4);
        sum += __shfl_xor(sum, 8);
        int e = ebase + w * 16 + lq * 4 + r;
        if (lr == 0 && e < n_edges) out[e] = sum + b3[0];
    }
}

extern "C" void kernel_launch(void* const* d_in, const int* in_sizes, int n_in,
                              void* d_out, int out_size, void* d_ws, size_t ws_size,
                              hipStream_t stream) {
    const float* h_src     = (const float*)d_in[0];
    const float* h_dst     = (const float*)d_in[1];
    const int*   src_nodes = (const int*)d_in[2];
    const int*   dst_nodes = (const int*)d_in[3];
    const int*   etype     = (const int*)d_in[4];
    const float* W1        = (const float*)d_in[5];
    const float* b1        = (const float*)d_in[6];
    const float* bn_gamma  = (const float*)d_in[7];
    const float* bn_beta   = (const float*)d_in[8];
    const float* bn_mean   = (const float*)d_in[9];
    const float* bn_var    = (const float*)d_in[10];
    const float* emb       = (const float*)d_in[11];
    const float* W2        = (const float*)d_in[12];
    const float* b2        = (const float*)d_in[13];
    const float* W3        = (const float*)d_in[14];
    const float* b3        = (const float*)d_in[15];

    const int n_edges = in_sizes[2];
    const int n_nodes = in_sizes[0] / 256;

    // d_ws layout: B1p[65536 u16] | B2p[8192 u16] | sc[128] | sh[128] | Psrc | Pdst
    ushort* B1p = (ushort*)d_ws;
    ushort* B2p = B1p + 65536;
    float*  scp = (float*)(B2p + 8192);
    float*  shp = scp + HID;
    const size_t wbytes = (size_t)(65536 + 8192) * 2 + 256 * 4;   // 148480 B
    const size_t pbytes = (size_t)n_nodes * HID * 2;              // per P array
    ushort* Psrc = (ushort*)((char*)d_ws + wbytes);
    ushort* Pdst = Psrc + (size_t)n_nodes * HID;

    prep_kernel<<<(65536 + 8192 + HID + 255) / 256, 256, 0, stream>>>(
        W1, W2, bn_gamma, bn_beta, bn_mean, bn_var, emb, etype, B1p, B2p, scp, shp);

    const int egrid = (n_edges + ETILE - 1) / ETILE;

    if (ws_size >= wbytes + 2 * pbytes) {
        const int ntiles = (n_nodes + 63) / 64;
        const int nblk   = (ntiles + 2) / 3;     // 3 tiles/half per block
        proj_kernel<<<nblk, 256, 0, stream>>>(h_src, h_dst, B1p, b1,
                                              Psrc, Pdst, n_nodes, ntiles, nblk);
        edge_kernel<<<egrid, 256, 0, stream>>>(Psrc, Pdst, src_nodes, dst_nodes,
                                               scp, shp, b2, W3, b3, B2p,
                                               (float*)d_out, n_edges);
    } else {
        edge_mlp_mfma<<<egrid, 256, 0, stream>>>(h_src, h_dst, src_nodes, dst_nodes,
                                                 B1p, B2p, b1, scp, shp, b2, W3, b3,
                                                 (float*)d_out, n_edges);
    }
}

// Round 18
// 90.752 us; speedup vs baseline: 1.1203x; 1.1203x over previous
//
#include <hip/hip_runtime.h>
#include <hip/hip_bf16.h>

// MultiEdgeTypePredictor — R15: R13 champion proj (v3) + B2-hoisted edge.
//
//   Psrc = h_src @ W1[:256,:] ; Pdst = h_dst @ W1[256:,:] + b1   (bf16, d_ws)
//   x[e] = relu(Psrc[s[e]] + Pdst[d[e]]) * sc + sh ; GEMM2 ; GEMM3
//
//   Single-variable change vs R13 (87.4us): edge_kernel hoists the 16
//   loop-invariant B2 fragments into registers at kernel entry (their L2
//   latency hides under index-load + gather) — R14 bundled this with a proj
//   regression; this round isolates it.

typedef __attribute__((ext_vector_type(8))) short bf16x8;
typedef __attribute__((ext_vector_type(4))) float f32x4;
typedef __attribute__((ext_vector_type(8))) unsigned short u16x8;

constexpr int HID   = 128;
constexpr int ETILE = 64;
constexpr int AS    = 72;    // fallback chunk stride (bf16 elems)
constexpr int XS    = 136;   // edge x-tile row stride (bf16 elems, 272B)
constexpr int PS    = 264;   // proj A-tile row stride (bf16 elems, 528B)

__device__ inline ushort f2bf(float f) {
    union { __hip_bfloat16 h; ushort u; } cv;
    cv.h = __float2bfloat16(f);   // RNE
    return cv.u;
}
__device__ inline float bf2f(ushort u) {
    return __uint_as_float(((unsigned int)u) << 16);
}

// ---------------- prep: pack weights + fold BN/emb ----------------
__global__ __launch_bounds__(256)
void prep_kernel(const float* __restrict__ W1, const float* __restrict__ W2,
                 const float* __restrict__ bn_gamma, const float* __restrict__ bn_beta,
                 const float* __restrict__ bn_mean, const float* __restrict__ bn_var,
                 const float* __restrict__ emb, const int* __restrict__ etype,
                 ushort* __restrict__ B1p, ushort* __restrict__ B2p,
                 float* __restrict__ sc, float* __restrict__ sh)
{
    int i = blockIdx.x * blockDim.x + threadIdx.x;
    if (i < 65536) {
        // B1 frag: i = ((ks*8 + ct)*64 + lane)*8 + j ; k = ks*32+(lane>>4)*8+j ; c = ct*16+(lane&15)
        int j = i & 7, lane = (i >> 3) & 63, ct = (i >> 9) & 7, ks = i >> 12;
        int k = ks * 32 + (lane >> 4) * 8 + j;
        int c = ct * 16 + (lane & 15);
        B1p[i] = f2bf(W1[k * HID + c]);
    } else if (i < 65536 + 8192) {
        int p = i - 65536;
        int j = p & 7, lane = (p >> 3) & 63, ct = (p >> 9) & 3, ks = p >> 11;
        int k = ks * 32 + (lane >> 4) * 8 + j;
        int c = ct * 16 + (lane & 15);
        B2p[p] = f2bf(W2[k * 64 + c]);
    } else if (i < 65536 + 8192 + HID) {
        int c = i - 65536 - 8192;
        float s = bn_gamma[c] * rsqrtf(bn_var[c] + 1e-5f);
        sc[c] = s;
        sh[c] = bn_beta[c] - bn_mean[c] * s + emb[etype[0] * HID + c];
    }
}

// ---------------- proj v3 (R13 champion): P = h @ W1_half (+b1 on dst) --------
// grid = NBLK blocks; block b does tiles {b, b+NBLK, b+2*NBLK} for each half.
__global__ __launch_bounds__(256)
void proj_kernel(const float* __restrict__ h_src, const float* __restrict__ h_dst,
                 const ushort* __restrict__ B1p, const float* __restrict__ b1,
                 ushort* __restrict__ Psrc, ushort* __restrict__ Pdst,
                 int n_nodes, int ntiles, int nblk)
{
    __shared__ ushort sA[ETILE * PS];     // 64 x 264 bf16 = 33792 B

    const int t    = threadIdx.x;
    const int lane = t & 63;
    const int w    = t >> 6;
    const int lr   = lane & 15;
    const int lq   = lane >> 4;

#pragma unroll 1
    for (int half = 0; half < 2; ++half) {
        const float* hp = half ? h_dst : h_src;
        ushort* Pp      = half ? Pdst : Psrc;

        // ---- B fragments for this half: 8 ksteps x 2 col-tiles, in registers ----
        bf16x8 bfr[8][2];
#pragma unroll
        for (int ks = 0; ks < 8; ++ks)
#pragma unroll
            for (int ctl = 0; ctl < 2; ++ctl)
                bfr[ks][ctl] = *reinterpret_cast<const bf16x8*>(
                    B1p + (size_t)(((half * 8 + ks) * 8 + 2 * w + ctl) * 64 + lane) * 8);

#pragma unroll 1
        for (int tile = blockIdx.x; tile < ntiles; tile += nblk) {
            const int nb = tile * 64;

            __syncthreads();   // prev tile's sA readers done

            // ---- stage full K: 64 rows x 256 cols, 4096 float4, 16/thread ----
#pragma unroll
            for (int i = 0; i < 16; ++i) {
                int f = t + i * 256;
                int e = f >> 6, q = f & 63;
                int row = nb + e;
                if (row >= n_nodes) row = n_nodes - 1;   // tail clamp (stores guarded)
                float4 v = *reinterpret_cast<const float4*>(
                    hp + (size_t)row * 256 + q * 4);
                ushort4 bv;
                bv.x = f2bf(v.x); bv.y = f2bf(v.y); bv.z = f2bf(v.z); bv.w = f2bf(v.w);
                *reinterpret_cast<ushort4*>(&sA[e * PS + q * 4]) = bv;
            }
            __syncthreads();

            // ---- MFMA: 8 K-slices x 4 row-tiles x 2 col-tiles, B from regs ----
            f32x4 acc[4][2];
#pragma unroll
            for (int rt = 0; rt < 4; ++rt)
#pragma unroll
                for (int c = 0; c < 2; ++c) acc[rt][c] = (f32x4)0.0f;

#pragma unroll
            for (int ks = 0; ks < 8; ++ks)
#pragma unroll
                for (int rt = 0; rt < 4; ++rt) {
                    bf16x8 af = *reinterpret_cast<const bf16x8*>(
                        &sA[(rt * 16 + lr) * PS + ks * 32 + lq * 8]);
                    acc[rt][0] = __builtin_amdgcn_mfma_f32_16x16x32_bf16(af, bfr[ks][0], acc[rt][0], 0, 0, 0);
                    acc[rt][1] = __builtin_amdgcn_mfma_f32_16x16x32_bf16(af, bfr[ks][1], acc[rt][1], 0, 0, 0);
                }

            __syncthreads();   // all sA readers done before X-tile overwrite

            // ---- epilogue: fold b1 on dst half; acc -> sA bf16 tile ----
#pragma unroll
            for (int ctl = 0; ctl < 2; ++ctl) {
                int c = (2 * w + ctl) * 16 + lr;
                float add = half ? b1[c] : 0.0f;
#pragma unroll
                for (int rt = 0; rt < 4; ++rt)
#pragma unroll
                    for (int r = 0; r < 4; ++r)
                        sA[(rt * 16 + lq * 4 + r) * PS + c] = f2bf(acc[rt][ctl][r] + add);
            }
            __syncthreads();

            // ---- cooperative coalesced store to P ----
#pragma unroll
            for (int i = 0; i < 4; ++i) {
                int f = t + i * 256;
                int e = f >> 4, q = f & 15;
                if (nb + e < n_nodes) {
                    u16x8 v = *reinterpret_cast<const u16x8*>(&sA[e * PS + q * 8]);
                    *reinterpret_cast<u16x8*>(Pp + (size_t)(nb + e) * 128 + q * 8) = v;
                }
            }
        }
    }
}

// ---------------- edge: hoisted B2 + coalesced gather + GEMM2/3 ----------------
__global__ __launch_bounds__(256)
void edge_kernel(const ushort* __restrict__ Psrc, const ushort* __restrict__ Pdst,
                 const int* __restrict__ src_nodes, const int* __restrict__ dst_nodes,
                 const float* __restrict__ sc, const float* __restrict__ sh,
                 const float* __restrict__ b2, const float* __restrict__ W3,
                 const float* __restrict__ b3, const ushort* __restrict__ B2p,
                 float* __restrict__ out, int n_edges)
{
    __shared__ ushort sX[ETILE * XS];
    __shared__ int s_s[ETILE], s_d[ETILE];

    const int t     = threadIdx.x;
    const int lane  = t & 63;
    const int w     = t >> 6;
    const int lr    = lane & 15;
    const int lq    = lane >> 4;
    const int ebase = blockIdx.x * ETILE;

    // hoist B2 fragments (block-invariant): in flight during index load + gather
    bf16x8 b2r[4][4];   // [ks][ct]
#pragma unroll
    for (int ks = 0; ks < 4; ++ks)
#pragma unroll
        for (int ct = 0; ct < 4; ++ct)
            b2r[ks][ct] = *reinterpret_cast<const bf16x8*>(
                B2p + (size_t)((ks * 4 + ct) * 64 + lane) * 8);

    if (t < ETILE) {
        int e = ebase + t;
        s_s[t] = src_nodes[e < n_edges ? e : (n_edges - 1)];
    } else if (t < 2 * ETILE) {
        int e = ebase + t - ETILE;
        s_d[t - ETILE] = dst_nodes[e < n_edges ? e : (n_edges - 1)];
    }
    __syncthreads();

    // gather: 16 lanes per P row (256B contiguous segments)
    const int eg = w * 16 + lq;
    const int ch = lr;
    u16x8 gs[4], gd[4];
#pragma unroll
    for (int j = 0; j < 4; ++j)
        gs[j] = *reinterpret_cast<const u16x8*>(
            Psrc + (size_t)s_s[eg + j * 4] * 128 + ch * 8);
#pragma unroll
    for (int j = 0; j < 4; ++j)
        gd[j] = *reinterpret_cast<const u16x8*>(
            Pdst + (size_t)s_d[eg + j * 4] * 128 + ch * 8);
    asm volatile("" :: "v"(gs[0]), "v"(gs[1]), "v"(gs[2]), "v"(gs[3]),
                       "v"(gd[0]), "v"(gd[1]), "v"(gd[2]), "v"(gd[3]));

    // decode: relu(a+b) * sc + sh -> x (bf16) in LDS
    const int c0 = ch * 8;
    float4 sca = *reinterpret_cast<const float4*>(sc + c0);
    float4 scb = *reinterpret_cast<const float4*>(sc + c0 + 4);
    float4 sha = *reinterpret_cast<const float4*>(sh + c0);
    float4 shb = *reinterpret_cast<const float4*>(sh + c0 + 4);
    float ss[8] = {sca.x, sca.y, sca.z, sca.w, scb.x, scb.y, scb.z, scb.w};
    float zz[8] = {sha.x, sha.y, sha.z, sha.w, shb.x, shb.y, shb.z, shb.w};
#pragma unroll
    for (int j = 0; j < 4; ++j) {
        u16x8 xo;
#pragma unroll
        for (int i = 0; i < 8; ++i) {
            float v = bf2f((ushort)gs[j][i]) + bf2f((ushort)gd[j][i]);
            v = fmaxf(v, 0.0f);
            xo[i] = f2bf(fmaf(v, ss[i], zz[i]));
        }
        *reinterpret_cast<u16x8*>(&sX[(eg + j * 4) * XS + c0]) = xo;
    }
    __syncthreads();

    // -------- GEMM2 (B from regs) --------
    f32x4 acc2[4];
#pragma unroll
    for (int ct = 0; ct < 4; ++ct) acc2[ct] = (f32x4)0.0f;

#pragma unroll
    for (int ks = 0; ks < 4; ++ks) {
        bf16x8 af = *reinterpret_cast<const bf16x8*>(
            &sX[(w * 16 + lr) * XS + ks * 32 + lq * 8]);
#pragma unroll
        for (int ct = 0; ct < 4; ++ct)
            acc2[ct] = __builtin_amdgcn_mfma_f32_16x16x32_bf16(af, b2r[ks][ct], acc2[ct], 0, 0, 0);
    }

    // -------- GEMM3 --------
    float w3v[4], b2v[4];
#pragma unroll
    for (int ct = 0; ct < 4; ++ct) {
        int c = ct * 16 + lr;
        w3v[ct] = W3[c];
        b2v[ct] = b2[c];
    }
#pragma unroll
    for (int r = 0; r < 4; ++r) {
        float sum = 0.0f;
#pragma unroll
        for (int ct = 0; ct < 4; ++ct)
            sum += fmaxf(acc2[ct][r] + b2v[ct], 0.0f) * w3v[ct];
        sum += __shfl_xor(sum, 1);
        sum += __shfl_xor(sum, 2);
        sum += __shfl_xor(sum, 4);
        sum += __shfl_xor(sum, 8);
        int eo = ebase + w * 16 + lq * 4 + r;
        if (lr == 0 && eo < n_edges) out[eo] = sum + b3[0];
    }
}

// ================= fallback: R10 champion fused path (97.7us) =================
__global__ __launch_bounds__(256, 3)
void edge_mlp_mfma(const float* __restrict__ h_src, const float* __restrict__ h_dst,
                   const int* __restrict__ src_nodes, const int* __restrict__ dst_nodes,
                   const ushort* __restrict__ B1p, const ushort* __restrict__ B2p,
                   const float* __restrict__ b1, const float* __restrict__ sc,
                   const float* __restrict__ sh, const float* __restrict__ b2,
                   const float* __restrict__ W3, const float* __restrict__ b3,
                   float* __restrict__ out, int n_edges)
{
    __shared__ ushort sA[2][ETILE * AS];
    __shared__ int s_src[ETILE], s_dst[ETILE];

    const int t    = threadIdx.x;
    const int lane = t & 63;
    const int w    = t >> 6;
    const int lr   = lane & 15;
    const int lq   = lane >> 4;
    const int ebase = blockIdx.x * ETILE;

    if (t < ETILE) {
        int e = ebase + t;
        s_src[t] = src_nodes[e < n_edges ? e : 0];
    } else if (t < 2 * ETILE) {
        int e = ebase + t - ETILE;
        s_dst[t - ETILE] = dst_nodes[e < n_edges ? e : 0];
    }

    f32x4 acc[4][2];
#pragma unroll
    for (int rt = 0; rt < 4; ++rt)
#pragma unroll
        for (int c = 0; c < 2; ++c) acc[rt][c] = (f32x4)0.0f;

    float4 rA[4], rB[4];
    bf16x8 Bf0[4], Bf1[4];

#define PHASE_BAR() do {                                                       \
        asm volatile("s_waitcnt lgkmcnt(0)" ::: "memory");                     \
        __builtin_amdgcn_s_barrier();                                          \
    } while (0)
#define PIN() __builtin_amdgcn_sched_barrier(0)

#define LOADC(kc, R) do {                                                      \
        const float* hp = ((kc) < 4) ? h_src : h_dst;                          \
        const int* sidx = ((kc) < 4) ? s_src : s_dst;                          \
        const int koff = ((kc) & 3) * 64;                                      \
        _Pragma("unroll")                                                      \
        for (int i = 0; i < 4; ++i) {                                          \
            int f = t + i * 256; int e = f >> 4; int q = f & 15;               \
            R[i] = *reinterpret_cast<const float4*>(                           \
                hp + (size_t)sidx[e] * 256 + koff + q * 4);                    \
        } } while (0)

#define BLOAD(kc, BR) do {                                                     \
        _Pragma("unroll")                                                      \
        for (int s = 0; s < 2; ++s)                                            \
        _Pragma("unroll")                                                      \
        for (int c = 0; c < 2; ++c)                                            \
            BR[s * 2 + c] = *reinterpret_cast<const bf16x8*>(                  \
                B1p + (size_t)((((kc) * 2 + s) * 8 + 2 * w + c) * 64 + lane) * 8); \
        } while (0)

#define STOREC(B, R) do {                                                      \
        _Pragma("unroll")                                                      \
        for (int i = 0; i < 4; ++i) {                                          \
            int f = t + i * 256; int e = f >> 4; int q = f & 15;               \
            ushort4 bv;                                                        \
            bv.x = f2bf(R[i].x); bv.y = f2bf(R[i].y);                          \
            bv.z = f2bf(R[i].z); bv.w = f2bf(R[i].w);                          \
            *reinterpret_cast<ushort4*>(&sA[B][e * AS + q * 4]) = bv;          \
        } } while (0)

#define COMPF(B, BR) do {                                                      \
        _Pragma("unroll")                                                      \
        for (int ks = 0; ks < 2; ++ks) {                                       \
            _Pragma("unroll")                                                  \
            for (int rt = 0; rt < 4; ++rt) {                                   \
                bf16x8 af = *reinterpret_cast<const bf16x8*>(                  \
                    &sA[B][(rt * 16 + lr) * AS + ks * 32 + lq * 8]);           \
                acc[rt][0] = __builtin_amdgcn_mfma_f32_16x16x32_bf16(af, BR[ks * 2 + 0], acc[rt][0], 0, 0, 0); \
                acc[rt][1] = __builtin_amdgcn_mfma_f32_16x16x32_bf16(af, BR[ks * 2 + 1], acc[rt][1], 0, 0, 0); \
            } } } while (0)

    __syncthreads();

    LOADC(0, rA);
    BLOAD(0, Bf0);
    STOREC(0, rA);
    LOADC(1, rB);
    BLOAD(1, Bf1);
    PHASE_BAR();

    LOADC(2, rA);  PIN();  COMPF(0, Bf0);  BLOAD(2, Bf0);  STOREC(1, rB);  PHASE_BAR();
    LOADC(3, rB);  PIN();  COMPF(1, Bf1);  BLOAD(3, Bf1);  STOREC(0, rA);  PHASE_BAR();
    LOADC(4, rA);  PIN();  COMPF(0, Bf0);  BLOAD(4, Bf0);  STOREC(1, rB);  PHASE_BAR();
    LOADC(5, rB);  PIN();  COMPF(1, Bf1);  BLOAD(5, Bf1);  STOREC(0, rA);  PHASE_BAR();
    LOADC(6, rA);  PIN();  COMPF(0, Bf0);  BLOAD(6, Bf0);  STOREC(1, rB);  PHASE_BAR();
    LOADC(7, rB);  PIN();  COMPF(1, Bf1);  BLOAD(7, Bf1);  STOREC(0, rA);  PHASE_BAR();
                           COMPF(0, Bf0);                  STOREC(1, rB);  PHASE_BAR();
                           COMPF(1, Bf1);

#undef LOADC
#undef BLOAD
#undef STOREC
#undef COMPF
#undef PIN
#undef PHASE_BAR

    __syncthreads();
    ushort* sX = &sA[0][0];
#pragma unroll
    for (int ctl = 0; ctl < 2; ++ctl) {
        int c = (2 * w + ctl) * 16 + lr;
        float bb = b1[c], s = sc[c], z = sh[c];
#pragma unroll
        for (int rt = 0; rt < 4; ++rt)
#pragma unroll
            for (int r = 0; r < 4; ++r) {
                float x = fmaxf(acc[rt][ctl][r] + bb, 0.0f);
                sX[(rt * 16 + lq * 4 + r) * XS + c] = f2bf(fmaf(x, s, z));
            }
    }
    __syncthreads();

    f32x4 acc2[4];
#pragma unroll
    for (int ct = 0; ct < 4; ++ct) acc2[ct] = (f32x4)0.0f;

#pragma unroll
    for (int ks = 0; ks < 4; ++ks) {
        bf16x8 af = *reinterpret_cast<const bf16x8*>(
            &sX[(w * 16 + lr) * XS + ks * 32 + lq * 8]);
#pragma unroll
        for (int ct = 0; ct < 4; ++ct) {
            bf16x8 bf = *reinterpret_cast<const bf16x8*>(
                B2p + (size_t)((ks * 4 + ct) * 64 + lane) * 8);
            acc2[ct] = __builtin_amdgcn_mfma_f32_16x16x32_bf16(af, bf, acc2[ct], 0, 0, 0);
        }
    }

    float w3v[4], b2v[4];
#pragma unroll
    for (int ct = 0; ct < 4; ++ct) {
        int c = ct * 16 + lr;
        w3v[ct] = W3[c];
        b2v[ct] = b2[c];
    }
#pragma unroll
    for (int r = 0; r < 4; ++r) {
        float sum = 0.0f;
#pragma unroll
        for (int ct = 0; ct < 4; ++ct)
            sum += fmaxf(acc2[ct][r] + b2v[ct], 0.0f) * w3v[ct];
        sum += __shfl_xor(sum, 1);
        sum += __shfl_xor(sum, 2);
        sum += __shfl_xor(sum, 4);
        sum += __shfl_xor(sum, 8);
        int e = ebase + w * 16 + lq * 4 + r;
        if (lr == 0 && e < n_edges) out[e] = sum + b3[0];
    }
}

extern "C" void kernel_launch(void* const* d_in, const int* in_sizes, int n_in,
                              void* d_out, int out_size, void* d_ws, size_t ws_size,
                              hipStream_t stream) {
    const float* h_src     = (const float*)d_in[0];
    const float* h_dst     = (const float*)d_in[1];
    const int*   src_nodes = (const int*)d_in[2];
    const int*   dst_nodes = (const int*)d_in[3];
    const int*   etype     = (const int*)d_in[4];
    const float* W1        = (const float*)d_in[5];
    const float* b1        = (const float*)d_in[6];
    const float* bn_gamma  = (const float*)d_in[7];
    const float* bn_beta   = (const float*)d_in[8];
    const float* bn_mean   = (const float*)d_in[9];
    const float* bn_var    = (const float*)d_in[10];
    const float* emb       = (const float*)d_in[11];
    const float* W2        = (const float*)d_in[12];
    const float* b2        = (const float*)d_in[13];
    const float* W3        = (const float*)d_in[14];
    const float* b3        = (const float*)d_in[15];

    const int n_edges = in_sizes[2];
    const int n_nodes = in_sizes[0] / 256;

    // d_ws layout: B1p[65536 u16] | B2p[8192 u16] | sc[128] | sh[128] | Psrc | Pdst
    ushort* B1p = (ushort*)d_ws;
    ushort* B2p = B1p + 65536;
    float*  scp = (float*)(B2p + 8192);
    float*  shp = scp + HID;
    const size_t wbytes = (size_t)(65536 + 8192) * 2 + 256 * 4;   // 148480 B
    const size_t pbytes = (size_t)n_nodes * HID * 2;              // per P array
    ushort* Psrc = (ushort*)((char*)d_ws + wbytes);
    ushort* Pdst = Psrc + (size_t)n_nodes * HID;

    prep_kernel<<<(65536 + 8192 + HID + 255) / 256, 256, 0, stream>>>(
        W1, W2, bn_gamma, bn_beta, bn_mean, bn_var, emb, etype, B1p, B2p, scp, shp);

    const int egrid = (n_edges + ETILE - 1) / ETILE;

    if (ws_size >= wbytes + 2 * pbytes) {
        const int ntiles = (n_nodes + 63) / 64;
        const int nblk   = (ntiles + 2) / 3;     // 3 tiles/half per block
        proj_kernel<<<nblk, 256, 0, stream>>>(h_src, h_dst, B1p, b1,
                                              Psrc, Pdst, n_nodes, ntiles, nblk);
        edge_kernel<<<egrid, 256, 0, stream>>>(Psrc, Pdst, src_nodes, dst_nodes,
                                               scp, shp, b2, W3, b3, B2p,
                                               (float*)d_out, n_edges);
    } else {
        edge_mlp_mfma<<<egrid, 256, 0, stream>>>(h_src, h_dst, src_nodes, dst_nodes,
                                                 B1p, B2p, b1, scp, shp, b2, W3, b3,
                                                 (float*)d_out, n_edges);
    }
}

// Round 19
// 87.076 us; speedup vs baseline: 1.1676x; 1.0422x over previous
//
#include <hip/hip_runtime.h>
#include <hip/hip_bf16.h>

// MultiEdgeTypePredictor — R16: revert to R13 champion verbatim (87.4us).
// R15's B2-hoist was neutral/negative (90.8) — same-FIFO latency was already
// hidden. Locking the champion: proj v3 (B1-frags in registers, full-K stage,
// 3 tiles/half per block) + simple edge + fused fallback.
//
//   Psrc = h_src @ W1[:256,:] ; Pdst = h_dst @ W1[256:,:] + b1   (bf16, d_ws)
//   x[e] = relu(Psrc[s[e]] + Pdst[d[e]]) * sc + sh ; GEMM2 ; GEMM3

typedef __attribute__((ext_vector_type(8))) short bf16x8;
typedef __attribute__((ext_vector_type(4))) float f32x4;
typedef __attribute__((ext_vector_type(8))) unsigned short u16x8;

constexpr int HID   = 128;
constexpr int ETILE = 64;
constexpr int AS    = 72;    // fallback chunk stride (bf16 elems)
constexpr int XS    = 136;   // edge x-tile row stride (bf16 elems, 272B)
constexpr int PS    = 264;   // proj A-tile row stride (bf16 elems, 528B)

__device__ inline ushort f2bf(float f) {
    union { __hip_bfloat16 h; ushort u; } cv;
    cv.h = __float2bfloat16(f);   // RNE
    return cv.u;
}
__device__ inline float bf2f(ushort u) {
    return __uint_as_float(((unsigned int)u) << 16);
}

// ---------------- prep: pack weights + fold BN/emb ----------------
__global__ __launch_bounds__(256)
void prep_kernel(const float* __restrict__ W1, const float* __restrict__ W2,
                 const float* __restrict__ bn_gamma, const float* __restrict__ bn_beta,
                 const float* __restrict__ bn_mean, const float* __restrict__ bn_var,
                 const float* __restrict__ emb, const int* __restrict__ etype,
                 ushort* __restrict__ B1p, ushort* __restrict__ B2p,
                 float* __restrict__ sc, float* __restrict__ sh)
{
    int i = blockIdx.x * blockDim.x + threadIdx.x;
    if (i < 65536) {
        // B1 frag: i = ((ks*8 + ct)*64 + lane)*8 + j ; k = ks*32+(lane>>4)*8+j ; c = ct*16+(lane&15)
        int j = i & 7, lane = (i >> 3) & 63, ct = (i >> 9) & 7, ks = i >> 12;
        int k = ks * 32 + (lane >> 4) * 8 + j;
        int c = ct * 16 + (lane & 15);
        B1p[i] = f2bf(W1[k * HID + c]);
    } else if (i < 65536 + 8192) {
        int p = i - 65536;
        int j = p & 7, lane = (p >> 3) & 63, ct = (p >> 9) & 3, ks = p >> 11;
        int k = ks * 32 + (lane >> 4) * 8 + j;
        int c = ct * 16 + (lane & 15);
        B2p[p] = f2bf(W2[k * 64 + c]);
    } else if (i < 65536 + 8192 + HID) {
        int c = i - 65536 - 8192;
        float s = bn_gamma[c] * rsqrtf(bn_var[c] + 1e-5f);
        sc[c] = s;
        sh[c] = bn_beta[c] - bn_mean[c] * s + emb[etype[0] * HID + c];
    }
}

// ---------------- proj v3: P = h @ W1_half (+b1 on dst half) ----------------
// grid = NBLK blocks; block b does tiles {b, b+NBLK, b+2*NBLK} for each half.
__global__ __launch_bounds__(256)
void proj_kernel(const float* __restrict__ h_src, const float* __restrict__ h_dst,
                 const ushort* __restrict__ B1p, const float* __restrict__ b1,
                 ushort* __restrict__ Psrc, ushort* __restrict__ Pdst,
                 int n_nodes, int ntiles, int nblk)
{
    __shared__ ushort sA[ETILE * PS];     // 64 x 264 bf16 = 33792 B

    const int t    = threadIdx.x;
    const int lane = t & 63;
    const int w    = t >> 6;
    const int lr   = lane & 15;
    const int lq   = lane >> 4;

#pragma unroll 1
    for (int half = 0; half < 2; ++half) {
        const float* hp = half ? h_dst : h_src;
        ushort* Pp      = half ? Pdst : Psrc;

        // ---- B fragments for this half: 8 ksteps x 2 col-tiles, in registers ----
        bf16x8 bfr[8][2];
#pragma unroll
        for (int ks = 0; ks < 8; ++ks)
#pragma unroll
            for (int ctl = 0; ctl < 2; ++ctl)
                bfr[ks][ctl] = *reinterpret_cast<const bf16x8*>(
                    B1p + (size_t)(((half * 8 + ks) * 8 + 2 * w + ctl) * 64 + lane) * 8);

#pragma unroll 1
        for (int tile = blockIdx.x; tile < ntiles; tile += nblk) {
            const int nb = tile * 64;

            __syncthreads();   // prev tile's sA readers done

            // ---- stage full K: 64 rows x 256 cols, 4096 float4, 16/thread ----
#pragma unroll
            for (int i = 0; i < 16; ++i) {
                int f = t + i * 256;
                int e = f >> 6, q = f & 63;
                int row = nb + e;
                if (row >= n_nodes) row = n_nodes - 1;   // tail clamp (stores guarded)
                float4 v = *reinterpret_cast<const float4*>(
                    hp + (size_t)row * 256 + q * 4);
                ushort4 bv;
                bv.x = f2bf(v.x); bv.y = f2bf(v.y); bv.z = f2bf(v.z); bv.w = f2bf(v.w);
                *reinterpret_cast<ushort4*>(&sA[e * PS + q * 4]) = bv;
            }
            __syncthreads();

            // ---- MFMA: 8 K-slices x 4 row-tiles x 2 col-tiles, B from regs ----
            f32x4 acc[4][2];
#pragma unroll
            for (int rt = 0; rt < 4; ++rt)
#pragma unroll
                for (int c = 0; c < 2; ++c) acc[rt][c] = (f32x4)0.0f;

#pragma unroll
            for (int ks = 0; ks < 8; ++ks)
#pragma unroll
                for (int rt = 0; rt < 4; ++rt) {
                    bf16x8 af = *reinterpret_cast<const bf16x8*>(
                        &sA[(rt * 16 + lr) * PS + ks * 32 + lq * 8]);
                    acc[rt][0] = __builtin_amdgcn_mfma_f32_16x16x32_bf16(af, bfr[ks][0], acc[rt][0], 0, 0, 0);
                    acc[rt][1] = __builtin_amdgcn_mfma_f32_16x16x32_bf16(af, bfr[ks][1], acc[rt][1], 0, 0, 0);
                }

            __syncthreads();   // all sA readers done before X-tile overwrite

            // ---- epilogue: fold b1 on dst half; acc -> sA bf16 tile ----
#pragma unroll
            for (int ctl = 0; ctl < 2; ++ctl) {
                int c = (2 * w + ctl) * 16 + lr;
                float add = half ? b1[c] : 0.0f;
#pragma unroll
                for (int rt = 0; rt < 4; ++rt)
#pragma unroll
                    for (int r = 0; r < 4; ++r)
                        sA[(rt * 16 + lq * 4 + r) * PS + c] = f2bf(acc[rt][ctl][r] + add);
            }
            __syncthreads();

            // ---- cooperative coalesced store to P ----
#pragma unroll
            for (int i = 0; i < 4; ++i) {
                int f = t + i * 256;
                int e = f >> 4, q = f & 15;
                if (nb + e < n_nodes) {
                    u16x8 v = *reinterpret_cast<const u16x8*>(&sA[e * PS + q * 8]);
                    *reinterpret_cast<u16x8*>(Pp + (size_t)(nb + e) * 128 + q * 8) = v;
                }
            }
        }
    }
}

// ---------------- edge: coalesced gather + fuse + GEMM2/3 ----------------
__global__ __launch_bounds__(256)
void edge_kernel(const ushort* __restrict__ Psrc, const ushort* __restrict__ Pdst,
                 const int* __restrict__ src_nodes, const int* __restrict__ dst_nodes,
                 const float* __restrict__ sc, const float* __restrict__ sh,
                 const float* __restrict__ b2, const float* __restrict__ W3,
                 const float* __restrict__ b3, const ushort* __restrict__ B2p,
                 float* __restrict__ out, int n_edges)
{
    __shared__ ushort sX[ETILE * XS];
    __shared__ int s_s[ETILE], s_d[ETILE];

    const int t     = threadIdx.x;
    const int lane  = t & 63;
    const int w     = t >> 6;
    const int lr    = lane & 15;
    const int lq    = lane >> 4;
    const int ebase = blockIdx.x * ETILE;

    if (t < ETILE) {
        int e = ebase + t;
        s_s[t] = src_nodes[e < n_edges ? e : (n_edges - 1)];
    } else if (t < 2 * ETILE) {
        int e = ebase + t - ETILE;
        s_d[t - ETILE] = dst_nodes[e < n_edges ? e : (n_edges - 1)];
    }
    __syncthreads();

    // gather: 16 lanes per P row (256B contiguous segments)
    const int eg = w * 16 + lq;
    const int ch = lr;
    u16x8 gs[4], gd[4];
#pragma unroll
    for (int j = 0; j < 4; ++j)
        gs[j] = *reinterpret_cast<const u16x8*>(
            Psrc + (size_t)s_s[eg + j * 4] * 128 + ch * 8);
#pragma unroll
    for (int j = 0; j < 4; ++j)
        gd[j] = *reinterpret_cast<const u16x8*>(
            Pdst + (size_t)s_d[eg + j * 4] * 128 + ch * 8);
    asm volatile("" :: "v"(gs[0]), "v"(gs[1]), "v"(gs[2]), "v"(gs[3]),
                       "v"(gd[0]), "v"(gd[1]), "v"(gd[2]), "v"(gd[3]));

    // decode: relu(a+b) * sc + sh -> x (bf16) in LDS
    const int c0 = ch * 8;
    float4 sca = *reinterpret_cast<const float4*>(sc + c0);
    float4 scb = *reinterpret_cast<const float4*>(sc + c0 + 4);
    float4 sha = *reinterpret_cast<const float4*>(sh + c0);
    float4 shb = *reinterpret_cast<const float4*>(sh + c0 + 4);
    float ss[8] = {sca.x, sca.y, sca.z, sca.w, scb.x, scb.y, scb.z, scb.w};
    float zz[8] = {sha.x, sha.y, sha.z, sha.w, shb.x, shb.y, shb.z, shb.w};
#pragma unroll
    for (int j = 0; j < 4; ++j) {
        u16x8 xo;
#pragma unroll
        for (int i = 0; i < 8; ++i) {
            float v = bf2f((ushort)gs[j][i]) + bf2f((ushort)gd[j][i]);
            v = fmaxf(v, 0.0f);
            xo[i] = f2bf(fmaf(v, ss[i], zz[i]));
        }
        *reinterpret_cast<u16x8*>(&sX[(eg + j * 4) * XS + c0]) = xo;
    }
    __syncthreads();

    // -------- GEMM2 --------
    f32x4 acc2[4];
#pragma unroll
    for (int ct = 0; ct < 4; ++ct) acc2[ct] = (f32x4)0.0f;

#pragma unroll
    for (int ks = 0; ks < 4; ++ks) {
        bf16x8 af = *reinterpret_cast<const bf16x8*>(
            &sX[(w * 16 + lr) * XS + ks * 32 + lq * 8]);
#pragma unroll
        for (int ct = 0; ct < 4; ++ct) {
            bf16x8 bf = *reinterpret_cast<const bf16x8*>(
                B2p + (size_t)((ks * 4 + ct) * 64 + lane) * 8);
            acc2[ct] = __builtin_amdgcn_mfma_f32_16x16x32_bf16(af, bf, acc2[ct], 0, 0, 0);
        }
    }

    // -------- GEMM3 --------
    float w3v[4], b2v[4];
#pragma unroll
    for (int ct = 0; ct < 4; ++ct) {
        int c = ct * 16 + lr;
        w3v[ct] = W3[c];
        b2v[ct] = b2[c];
    }
#pragma unroll
    for (int r = 0; r < 4; ++r) {
        float sum = 0.0f;
#pragma unroll
        for (int ct = 0; ct < 4; ++ct)
            sum += fmaxf(acc2[ct][r] + b2v[ct], 0.0f) * w3v[ct];
        sum += __shfl_xor(sum, 1);
        sum += __shfl_xor(sum, 2);
        sum += __shfl_xor(sum, 4);
        sum += __shfl_xor(sum, 8);
        int eo = ebase + w * 16 + lq * 4 + r;
        if (lr == 0 && eo < n_edges) out[eo] = sum + b3[0];
    }
}

// ================= fallback: R10 champion fused path (97.7us) =================
__global__ __launch_bounds__(256, 3)
void edge_mlp_mfma(const float* __restrict__ h_src, const float* __restrict__ h_dst,
                   const int* __restrict__ src_nodes, const int* __restrict__ dst_nodes,
                   const ushort* __restrict__ B1p, const ushort* __restrict__ B2p,
                   const float* __restrict__ b1, const float* __restrict__ sc,
                   const float* __restrict__ sh, const float* __restrict__ b2,
                   const float* __restrict__ W3, const float* __restrict__ b3,
                   float* __restrict__ out, int n_edges)
{
    __shared__ ushort sA[2][ETILE * AS];
    __shared__ int s_src[ETILE], s_dst[ETILE];

    const int t    = threadIdx.x;
    const int lane = t & 63;
    const int w    = t >> 6;
    const int lr   = lane & 15;
    const int lq   = lane >> 4;
    const int ebase = blockIdx.x * ETILE;

    if (t < ETILE) {
        int e = ebase + t;
        s_src[t] = src_nodes[e < n_edges ? e : 0];
    } else if (t < 2 * ETILE) {
        int e = ebase + t - ETILE;
        s_dst[t - ETILE] = dst_nodes[e < n_edges ? e : 0];
    }

    f32x4 acc[4][2];
#pragma unroll
    for (int rt = 0; rt < 4; ++rt)
#pragma unroll
        for (int c = 0; c < 2; ++c) acc[rt][c] = (f32x4)0.0f;

    float4 rA[4], rB[4];
    bf16x8 Bf0[4], Bf1[4];

#define PHASE_BAR() do {                                                       \
        asm volatile("s_waitcnt lgkmcnt(0)" ::: "memory");                     \
        __builtin_amdgcn_s_barrier();                                          \
    } while (0)
#define PIN() __builtin_amdgcn_sched_barrier(0)

#define LOADC(kc, R) do {                                                      \
        const float* hp = ((kc) < 4) ? h_src : h_dst;                          \
        const int* sidx = ((kc) < 4) ? s_src : s_dst;                          \
        const int koff = ((kc) & 3) * 64;                                      \
        _Pragma("unroll")                                                      \
        for (int i = 0; i < 4; ++i) {                                          \
            int f = t + i * 256; int e = f >> 4; int q = f & 15;               \
            R[i] = *reinterpret_cast<const float4*>(                           \
                hp + (size_t)sidx[e] * 256 + koff + q * 4);                    \
        } } while (0)

#define BLOAD(kc, BR) do {                                                     \
        _Pragma("unroll")                                                      \
        for (int s = 0; s < 2; ++s)                                            \
        _Pragma("unroll")                                                      \
        for (int c = 0; c < 2; ++c)                                            \
            BR[s * 2 + c] = *reinterpret_cast<const bf16x8*>(                  \
                B1p + (size_t)((((kc) * 2 + s) * 8 + 2 * w + c) * 64 + lane) * 8); \
        } while (0)

#define STOREC(B, R) do {                                                      \
        _Pragma("unroll")                                                      \
        for (int i = 0; i < 4; ++i) {                                          \
            int f = t + i * 256; int e = f >> 4; int q = f & 15;               \
            ushort4 bv;                                                        \
            bv.x = f2bf(R[i].x); bv.y = f2bf(R[i].y);                          \
            bv.z = f2bf(R[i].z); bv.w = f2bf(R[i].w);                          \
            *reinterpret_cast<ushort4*>(&sA[B][e * AS + q * 4]) = bv;          \
        } } while (0)

#define COMPF(B, BR) do {                                                      \
        _Pragma("unroll")                                                      \
        for (int ks = 0; ks < 2; ++ks) {                                       \
            _Pragma("unroll")                                                  \
            for (int rt = 0; rt < 4; ++rt) {                                   \
                bf16x8 af = *reinterpret_cast<const bf16x8*>(                  \
                    &sA[B][(rt * 16 + lr) * AS + ks * 32 + lq * 8]);           \
                acc[rt][0] = __builtin_amdgcn_mfma_f32_16x16x32_bf16(af, BR[ks * 2 + 0], acc[rt][0], 0, 0, 0); \
                acc[rt][1] = __builtin_amdgcn_mfma_f32_16x16x32_bf16(af, BR[ks * 2 + 1], acc[rt][1], 0, 0, 0); \
            } } } while (0)

    __syncthreads();

    LOADC(0, rA);
    BLOAD(0, Bf0);
    STOREC(0, rA);
    LOADC(1, rB);
    BLOAD(1, Bf1);
    PHASE_BAR();

    LOADC(2, rA);  PIN();  COMPF(0, Bf0);  BLOAD(2, Bf0);  STOREC(1, rB);  PHASE_BAR();
    LOADC(3, rB);  PIN();  COMPF(1, Bf1);  BLOAD(3, Bf1);  STOREC(0, rA);  PHASE_BAR();
    LOADC(4, rA);  PIN();  COMPF(0, Bf0);  BLOAD(4, Bf0);  STOREC(1, rB);  PHASE_BAR();
    LOADC(5, rB);  PIN();  COMPF(1, Bf1);  BLOAD(5, Bf1);  STOREC(0, rA);  PHASE_BAR();
    LOADC(6, rA);  PIN();  COMPF(0, Bf0);  BLOAD(6, Bf0);  STOREC(1, rB);  PHASE_BAR();
    LOADC(7, rB);  PIN();  COMPF(1, Bf1);  BLOAD(7, Bf1);  STOREC(0, rA);  PHASE_BAR();
                           COMPF(0, Bf0);                  STOREC(1, rB);  PHASE_BAR();
                           COMPF(1, Bf1);

#undef LOADC
#undef BLOAD
#undef STOREC
#undef COMPF
#undef PIN
#undef PHASE_BAR

    __syncthreads();
    ushort* sX = &sA[0][0];
#pragma unroll
    for (int ctl = 0; ctl < 2; ++ctl) {
        int c = (2 * w + ctl) * 16 + lr;
        float bb = b1[c], s = sc[c], z = sh[c];
#pragma unroll
        for (int rt = 0; rt < 4; ++rt)
#pragma unroll
            for (int r = 0; r < 4; ++r) {
                float x = fmaxf(acc[rt][ctl][r] + bb, 0.0f);
                sX[(rt * 16 + lq * 4 + r) * XS + c] = f2bf(fmaf(x, s, z));
            }
    }
    __syncthreads();

    f32x4 acc2[4];
#pragma unroll
    for (int ct = 0; ct < 4; ++ct) acc2[ct] = (f32x4)0.0f;

#pragma unroll
    for (int ks = 0; ks < 4; ++ks) {
        bf16x8 af = *reinterpret_cast<const bf16x8*>(
            &sX[(w * 16 + lr) * XS + ks * 32 + lq * 8]);
#pragma unroll
        for (int ct = 0; ct < 4; ++ct) {
            bf16x8 bf = *reinterpret_cast<const bf16x8*>(
                B2p + (size_t)((ks * 4 + ct) * 64 + lane) * 8);
            acc2[ct] = __builtin_amdgcn_mfma_f32_16x16x32_bf16(af, bf, acc2[ct], 0, 0, 0);
        }
    }

    float w3v[4], b2v[4];
#pragma unroll
    for (int ct = 0; ct < 4; ++ct) {
        int c = ct * 16 + lr;
        w3v[ct] = W3[c];
        b2v[ct] = b2[c];
    }
#pragma unroll
    for (int r = 0; r < 4; ++r) {
        float sum = 0.0f;
#pragma unroll
        for (int ct = 0; ct < 4; ++ct)
            sum += fmaxf(acc2[ct][r] + b2v[ct], 0.0f) * w3v[ct];
        sum += __shfl_xor(sum, 1);
        sum += __shfl_xor(sum, 2);
        sum += __shfl_xor(sum, 4);
        sum += __shfl_xor(sum, 8);
        int e = ebase + w * 16 + lq * 4 + r;
        if (lr == 0 && e < n_edges) out[e] = sum + b3[0];
    }
}

extern "C" void kernel_launch(void* const* d_in, const int* in_sizes, int n_in,
                              void* d_out, int out_size, void* d_ws, size_t ws_size,
                              hipStream_t stream) {
    const float* h_src     = (const float*)d_in[0];
    const float* h_dst     = (const float*)d_in[1];
    const int*   src_nodes = (const int*)d_in[2];
    const int*   dst_nodes = (const int*)d_in[3];
    const int*   etype     = (const int*)d_in[4];
    const float* W1        = (const float*)d_in[5];
    const float* b1        = (const float*)d_in[6];
    const float* bn_gamma  = (const float*)d_in[7];
    const float* bn_beta   = (const float*)d_in[8];
    const float* bn_mean   = (const float*)d_in[9];
    const float* bn_var    = (const float*)d_in[10];
    const float* emb       = (const float*)d_in[11];
    const float* W2        = (const float*)d_in[12];
    const float* b2        = (const float*)d_in[13];
    const float* W3        = (const float*)d_in[14];
    const float* b3        = (const float*)d_in[15];

    const int n_edges = in_sizes[2];
    const int n_nodes = in_sizes[0] / 256;

    // d_ws layout: B1p[65536 u16] | B2p[8192 u16] | sc[128] | sh[128] | Psrc | Pdst
    ushort* B1p = (ushort*)d_ws;
    ushort* B2p = B1p + 65536;
    float*  scp = (float*)(B2p + 8192);
    float*  shp = scp + HID;
    const size_t wbytes = (size_t)(65536 + 8192) * 2 + 256 * 4;   // 148480 B
    const size_t pbytes = (size_t)n_nodes * HID * 2;              // per P array
    ushort* Psrc = (ushort*)((char*)d_ws + wbytes);
    ushort* Pdst = Psrc + (size_t)n_nodes * HID;

    prep_kernel<<<(65536 + 8192 + HID + 255) / 256, 256, 0, stream>>>(
        W1, W2, bn_gamma, bn_beta, bn_mean, bn_var, emb, etype, B1p, B2p, scp, shp);

    const int egrid = (n_edges + ETILE - 1) / ETILE;

    if (ws_size >= wbytes + 2 * pbytes) {
        const int ntiles = (n_nodes + 63) / 64;
        const int nblk   = (ntiles + 2) / 3;     // 3 tiles/half per block
        proj_kernel<<<nblk, 256, 0, stream>>>(h_src, h_dst, B1p, b1,
                                              Psrc, Pdst, n_nodes, ntiles, nblk);
        edge_kernel<<<egrid, 256, 0, stream>>>(Psrc, Pdst, src_nodes, dst_nodes,
                                               scp, shp, b2, W3, b3, B2p,
                                               (float*)d_out, n_edges);
    } else {
        edge_mlp_mfma<<<egrid, 256, 0, stream>>>(h_src, h_dst, src_nodes, dst_nodes,
                                                 B1p, B2p, b1, scp, shp, b2, W3, b3,
                                                 (float*)d_out, n_edges);
    }
}